// Round 1
// baseline (419.559 us; speedup 1.0000x reference)
//
#include <hip/hip_runtime.h>
#include <stdint.h>

// AudioSNN: conv1(1->32,64x32)+spike+pool -> conv2(32->64,32x16)+spike+pool
// -> fc1 -> 25-step LIF recurrence (fc2, fc3). All fp32 (no fp32 MFMA on CDNA4;
// spikes are Heaviside => numerics must stay fp32-faithful).
//
// ws layout:
//   c1   u8  [1024][32][32][16]   16 MB   (pool counts 0..4; c1 float = n/4)
//   xq   u8  [1024][8192]          8 MB   (x_flat counts 0..4)
//   cur3 f32 [1024][256]           1 MB
//   w2t  f32 [256][128]          128 KB   (fc2_w transposed)
//   part f32 [32][1024][256]      32 MB   (fc1 K-split partials)

#define NSTEP 25

__device__ __forceinline__ float lif_update(float mem, float cur) {
#pragma clang fp contract(off)
  // snntorch Leaky, reset_mechanism='subtract': reset from PREVIOUS mem.
  // Mirror reference rounding exactly: mul, add, sub as separate roundings.
  float reset = (mem > 1.0f) ? 1.0f : 0.0f;
  float m = 0.95f * mem;
  m = m + cur;
  m = m - reset;
  return m;
}

// ---------------------------------------------------------------- w2 transpose
__global__ __launch_bounds__(256) void k_w2t(const float* __restrict__ w2,
                                             float* __restrict__ w2t) {
  // w2: [128][256] -> w2t: [256][128]
  const int j = blockIdx.x;    // 128
  const int i = threadIdx.x;   // 256
  w2t[i * 128 + j] = w2[j * 256 + i];
}

// ---------------------------------------------------------------- conv1 fused
__global__ __launch_bounds__(256) void k_conv1(const float* __restrict__ x,
                                               const float* __restrict__ w,
                                               const float* __restrict__ bias,
                                               uint8_t* __restrict__ c1) {
  __shared__ float xin[66 * 34];   // 64x32 + SAME halo, zero padded
  __shared__ float wl[288];
  __shared__ float bl[32];
  const int t = threadIdx.x;
  const int s = blockIdx.x;

  for (int idx = t; idx < 66 * 34; idx += 256) xin[idx] = 0.0f;
  wl[t] = w[t];                       // t<256
  if (t < 32) { wl[256 + t] = w[256 + t]; bl[t] = bias[t]; }
  __syncthreads();

  const float* xs = x + (size_t)s * (64 * 32);
#pragma unroll
  for (int r = 0; r < 2; ++r) {
    int idx = t + r * 256;            // 0..511 -> 64 rows x 8 quads
    int y = idx >> 3, q = idx & 7;
    float4 v = *(const float4*)(xs + y * 32 + q * 4);
    float* dst = &xin[(y + 1) * 34 + q * 4 + 1];
    dst[0] = v.x; dst[1] = v.y; dst[2] = v.z; dst[3] = v.w;
  }
  __syncthreads();

  uint8_t* c1s = c1 + (size_t)s * (32 * 32 * 16);
  for (int rr = 0; rr < 64; ++rr) {
    int idx = rr * 256 + t;           // ch wave-uniform (512 pos per ch)
    int ch = idx >> 9;
    int pos = idx & 511;
    int py = pos >> 4, px = pos & 15;
    const float* wc = &wl[ch * 9];
    float bv = bl[ch];
    float p[4][4];
#pragma unroll
    for (int rw = 0; rw < 4; ++rw) {
      float2 a = *(const float2*)&xin[(2 * py + rw) * 34 + 2 * px];
      float2 b = *(const float2*)&xin[(2 * py + rw) * 34 + 2 * px + 2];
      p[rw][0] = a.x; p[rw][1] = a.y; p[rw][2] = b.x; p[rw][3] = b.y;
    }
    int cnt = 0;
#pragma unroll
    for (int dy = 0; dy < 2; ++dy)
#pragma unroll
      for (int dx = 0; dx < 2; ++dx) {
        float acc = 0.0f;
#pragma unroll
        for (int ky = 0; ky < 3; ++ky)
#pragma unroll
          for (int kx = 0; kx < 3; ++kx)
            acc += wc[ky * 3 + kx] * p[dy + ky][dx + kx];
        float v = acc + bv;
        cnt += (v > 1.0f) ? 1 : 0;
      }
    c1s[ch * 512 + py * 16 + px] = (uint8_t)cnt;
  }
}

// ---------------------------------------------------------------- conv2 fused
__global__ __launch_bounds__(256) void k_conv2(const uint8_t* __restrict__ c1,
                                               const float* __restrict__ w,   // [64][32][9]
                                               const float* __restrict__ bias,
                                               uint8_t* __restrict__ xq) {
  // One block = one sample x one row-half (16 conv rows). LDS input 45 KB.
  __shared__ float cin[32 * 18 * 20];  // [c][r(18)][col(20 padded)], col0 = x=-1
  const int t = threadIdx.x;
  const int s = blockIdx.x >> 1;
  const int half = blockIdx.x & 1;

  for (int idx = t; idx < 32 * 18 * 20; idx += 256) cin[idx] = 0.0f;
  __syncthreads();

  const uint8_t* c1s = c1 + (size_t)s * (32 * 32 * 16);
  for (int idx = t; idx < 576; idx += 256) {   // 32 c x 18 rows
    int c = idx / 18, r = idx % 18;
    int y = half * 16 + r - 1;
    if (y >= 0 && y < 32) {
      const uchar4* src = (const uchar4*)(c1s + (c * 32 + y) * 16);
      float* dst = &cin[(c * 18 + r) * 20 + 1];
#pragma unroll
      for (int q = 0; q < 4; ++q) {
        uchar4 u = src[q];
        dst[q * 4 + 0] = (float)u.x; dst[q * 4 + 1] = (float)u.y;
        dst[q * 4 + 2] = (float)u.z; dst[q * 4 + 3] = (float)u.w;
      }
    }
  }
  __syncthreads();

  const int lane = t & 63;
  const int wav = __builtin_amdgcn_readfirstlane(t >> 6);  // wave-uniform -> s_load weights
  const int pr = lane >> 3, pc = lane & 7;                 // pooled pos in 8x8
  const int cr = 2 * pr, cc = 2 * pc;

  float acc[16][4];
#pragma unroll
  for (int a = 0; a < 16; ++a) {
    acc[a][0] = 0.f; acc[a][1] = 0.f; acc[a][2] = 0.f; acc[a][3] = 0.f;
  }

  for (int c = 0; c < 32; ++c) {
    float p[4][4];
#pragma unroll
    for (int rw = 0; rw < 4; ++rw) {
      float2 a = *(const float2*)&cin[(c * 18 + cr + rw) * 20 + cc];
      float2 b = *(const float2*)&cin[(c * 18 + cr + rw) * 20 + cc + 2];
      p[rw][0] = a.x; p[rw][1] = a.y; p[rw][2] = b.x; p[rw][3] = b.y;
    }
#pragma unroll
    for (int oci = 0; oci < 16; ++oci) {
      const float* wp = w + (size_t)((wav * 16 + oci) * 32 + c) * 9;  // uniform addr
      float w0 = wp[0], w1 = wp[1], w2 = wp[2], w3 = wp[3], w4 = wp[4],
            w5 = wp[5], w6 = wp[6], w7 = wp[7], w8 = wp[8];
#pragma unroll
      for (int dy = 0; dy < 2; ++dy)
#pragma unroll
        for (int dx = 0; dx < 2; ++dx) {
          float sum = acc[oci][dy * 2 + dx];
          sum += w0 * p[dy + 0][dx + 0];
          sum += w1 * p[dy + 0][dx + 1];
          sum += w2 * p[dy + 0][dx + 2];
          sum += w3 * p[dy + 1][dx + 0];
          sum += w4 * p[dy + 1][dx + 1];
          sum += w5 * p[dy + 1][dx + 2];
          sum += w6 * p[dy + 2][dx + 0];
          sum += w7 * p[dy + 2][dx + 1];
          sum += w8 * p[dy + 2][dx + 2];
          acc[oci][dy * 2 + dx] = sum;
        }
    }
  }

  uint8_t* xqs = xq + (size_t)s * 8192;
#pragma unroll
  for (int oci = 0; oci < 16; ++oci) {
    int oc = wav * 16 + oci;
    float bv = bias[oc];
    int cnt = 0;
#pragma unroll
    for (int pix = 0; pix < 4; ++pix) {
      // acc holds sum(w*n); 0.25*acc has identical roundings to sum(w*(n/4))
      float v = 0.25f * acc[oci][pix] + bv;
      cnt += (v > 1.0f) ? 1 : 0;
    }
    xqs[oc * 128 + (half * 8 + pr) * 8 + pc] = (uint8_t)cnt;
  }
}

// ---------------------------------------------------------------- fc1 (K-split)
__global__ __launch_bounds__(256) void k_fc1(const uint8_t* __restrict__ xq,
                                             const float* __restrict__ w1,  // [256][8192]
                                             float* __restrict__ part) {
  __shared__ float wT[32 * 256];  // [k][o]
  __shared__ float xT[32 * 68];   // [k][s], stride 68 (aligned + conflict-light)
  const int t = threadIdx.x;
  const int sblk = blockIdx.x >> 5;   // 16 sample tiles of 64
  const int kblk = blockIdx.x & 31;   // 32 K tiles of 256
  const int sb = sblk * 64;
  const int o_base = (t & 63) * 4;
  const int s_base = (t >> 6) * 16;

  float acc[4][16];
#pragma unroll
  for (int oi = 0; oi < 4; ++oi)
#pragma unroll
    for (int si = 0; si < 16; ++si) acc[oi][si] = 0.0f;

  for (int kc = 0; kc < 8; ++kc) {
    const int k0 = kblk * 256 + kc * 32;
    __syncthreads();
    {  // stage weights, coalesced 128B row chunks
      int li = t & 7, ob = t >> 3;
#pragma unroll
      for (int i = 0; i < 8; ++i) {
        int o = ob + 32 * i;
        float4 v = *(const float4*)(w1 + (size_t)o * 8192 + k0 + li * 4);
        wT[(li * 4 + 0) * 256 + o] = v.x;
        wT[(li * 4 + 1) * 256 + o] = v.y;
        wT[(li * 4 + 2) * 256 + o] = v.z;
        wT[(li * 4 + 3) * 256 + o] = v.w;
      }
    }
    {  // stage activations (u8 counts -> f32)
#pragma unroll
      for (int rep = 0; rep < 2; ++rep) {
        int idx = t + rep * 256;        // 64 s x 8 quads
        int si = idx >> 3, q = idx & 7;
        uchar4 u = *(const uchar4*)(xq + (size_t)(sb + si) * 8192 + k0 + q * 4);
        xT[(q * 4 + 0) * 68 + si] = (float)u.x;
        xT[(q * 4 + 1) * 68 + si] = (float)u.y;
        xT[(q * 4 + 2) * 68 + si] = (float)u.z;
        xT[(q * 4 + 3) * 68 + si] = (float)u.w;
      }
    }
    __syncthreads();
#pragma unroll 2
    for (int k = 0; k < 32; ++k) {
      float4 wv = *(const float4*)&wT[k * 256 + o_base];
      float4 x0 = *(const float4*)&xT[k * 68 + s_base];
      float4 x1 = *(const float4*)&xT[k * 68 + s_base + 4];
      float4 x2 = *(const float4*)&xT[k * 68 + s_base + 8];
      float4 x3 = *(const float4*)&xT[k * 68 + s_base + 12];
      float xs[16] = {x0.x, x0.y, x0.z, x0.w, x1.x, x1.y, x1.z, x1.w,
                      x2.x, x2.y, x2.z, x2.w, x3.x, x3.y, x3.z, x3.w};
      float wa[4] = {wv.x, wv.y, wv.z, wv.w};
#pragma unroll
      for (int oi = 0; oi < 4; ++oi)
#pragma unroll
        for (int si = 0; si < 16; ++si) acc[oi][si] += wa[oi] * xs[si];
    }
  }

  float* pout = part + (size_t)kblk * (1024 * 256);
#pragma unroll
  for (int oi = 0; oi < 4; ++oi)
#pragma unroll
    for (int si = 0; si < 16; ++si)
      pout[(size_t)(sb + s_base + si) * 256 + o_base + oi] = 0.25f * acc[oi][si];
}

__global__ __launch_bounds__(256) void k_fc1_reduce(const float* __restrict__ part,
                                                    const float* __restrict__ b1,
                                                    float* __restrict__ cur3) {
  int idx = blockIdx.x * 256 + threadIdx.x;  // 1024 blocks x 256
  int o = idx & 255;
  float s = 0.0f;
  for (int kb = 0; kb < 32; ++kb) s += part[(size_t)kb * (1024 * 256) + idx];
  cur3[idx] = s + b1[o];   // bias added last, like the reference
}

// ---------------------------------------------------------------- LIF recurrence
__global__ __launch_bounds__(512) void k_lif(const float* __restrict__ cur3,
                                             const float* __restrict__ w2t,  // [256][128]
                                             const float* __restrict__ b2,
                                             const float* __restrict__ w3,   // [10][128]
                                             const float* __restrict__ b3,
                                             float* __restrict__ out) {
  __shared__ float spk3f[256][4];
  __shared__ float part[4][128][4];
  __shared__ float spk4f[128][4];
  __shared__ float w3l[10 * 132];   // stride 132 kills bank aliasing across cls
  const int t = threadIdx.x;
  const int sb = blockIdx.x * 4;    // 4 samples per block, grid 256 = 1/CU

  for (int idx = t; idx < 1280; idx += 512) {
    int cls = idx >> 7, k = idx & 127;
    w3l[cls * 132 + k] = w3[idx];
  }
  // phase-1 state: thread (i3, sp) owns neurons i3 for samples sp*2, sp*2+1
  const int i3 = t & 255;
  const int sp = t >> 8;
  float mem3a = 0.0f, mem3b = 0.0f;
  const float cur3a = cur3[(size_t)(sb + sp * 2 + 0) * 256 + i3];
  const float cur3b = cur3[(size_t)(sb + sp * 2 + 1) * 256 + i3];
  // phase-2: j neuron, h quarter of the i-range
  const int j2 = t & 127;
  const int h2 = t >> 7;
  // phase-2b state (threads 0..127)
  float mem4[4] = {0.f, 0.f, 0.f, 0.f};
  const float b2v = (t < 128) ? b2[t] : 0.0f;
  // phase-3 state (threads 0..63 -> 4 samples x 16 slots, 10 active)
  const int s5 = t >> 4, cls5 = t & 15;
  float mem5 = 0.0f;
  const float b3v = (t < 64 && cls5 < 10) ? b3[cls5] : 0.0f;
  __syncthreads();

  for (int step = 0; step < NSTEP; ++step) {
    // ---- layer 3
    mem3a = lif_update(mem3a, cur3a);
    mem3b = lif_update(mem3b, cur3b);
    spk3f[i3][sp * 2 + 0] = (mem3a > 1.0f) ? 1.0f : 0.0f;
    spk3f[i3][sp * 2 + 1] = (mem3b > 1.0f) ? 1.0f : 0.0f;
    __syncthreads();
    // ---- layer 4 partial dot: w2t reads coalesced (lanes = consecutive j)
    {
      float a0 = 0.f, a1 = 0.f, a2 = 0.f, a3 = 0.f;
      const float* wp = w2t + (size_t)(h2 * 64) * 128 + j2;
      const float4* sp4 = (const float4*)&spk3f[h2 * 64][0];
#pragma unroll 8
      for (int ii = 0; ii < 64; ++ii) {
        float wv = wp[(size_t)ii * 128];
        float4 sv = sp4[ii];           // wave-uniform -> LDS broadcast
        a0 += wv * sv.x; a1 += wv * sv.y; a2 += wv * sv.z; a3 += wv * sv.w;
      }
      float4 pv = {a0, a1, a2, a3};
      *(float4*)&part[h2][j2][0] = pv;
    }
    __syncthreads();
    // ---- layer 4 combine + LIF
    if (t < 128) {
#pragma unroll
      for (int s = 0; s < 4; ++s) {
        float sum = (part[0][t][s] + part[1][t][s]) + (part[2][t][s] + part[3][t][s]);
        float cur4 = sum + b2v;
        mem4[s] = lif_update(mem4[s], cur4);
        spk4f[t][s] = (mem4[s] > 1.0f) ? 1.0f : 0.0f;
      }
    }
    __syncthreads();
    // ---- layer 5
    if (t < 64 && cls5 < 10) {
      float a5 = 0.0f;
#pragma unroll 8
      for (int k = 0; k < 128; ++k)
        a5 += spk4f[k][s5] * w3l[cls5 * 132 + k];
      float cur5 = a5 + b3v;
      mem5 = lif_update(mem5, cur5);
      out[(size_t)step * 10240 + (size_t)(sb + s5) * 10 + cls5] =
          (mem5 > 1.0f) ? 1.0f : 0.0f;
    }
    __syncthreads();
  }
}

// ---------------------------------------------------------------- launcher
extern "C" void kernel_launch(void* const* d_in, const int* in_sizes, int n_in,
                              void* d_out, int out_size, void* d_ws, size_t ws_size,
                              hipStream_t stream) {
  (void)in_sizes; (void)n_in; (void)out_size; (void)ws_size;
  const float* x   = (const float*)d_in[0];
  const float* w1c = (const float*)d_in[1];
  const float* b1c = (const float*)d_in[2];
  const float* w2c = (const float*)d_in[3];
  const float* b2c = (const float*)d_in[4];
  const float* fw1 = (const float*)d_in[5];
  const float* fb1 = (const float*)d_in[6];
  const float* fw2 = (const float*)d_in[7];
  const float* fb2 = (const float*)d_in[8];
  const float* fw3 = (const float*)d_in[9];
  const float* fb3 = (const float*)d_in[10];
  float* out = (float*)d_out;

  char* ws = (char*)d_ws;
  uint8_t* c1   = (uint8_t*)ws;                       // 16 MB
  uint8_t* xq   = (uint8_t*)(ws + (16u << 20));       //  8 MB
  float*   cur3 = (float*)(ws + (24u << 20));         //  1 MB
  float*   w2t  = (float*)(ws + (25u << 20));         // 128 KB
  float*   part = (float*)(ws + (26u << 20));         // 32 MB

  k_w2t<<<dim3(128), dim3(256), 0, stream>>>(fw2, w2t);
  k_conv1<<<dim3(1024), dim3(256), 0, stream>>>(x, w1c, b1c, c1);
  k_conv2<<<dim3(2048), dim3(256), 0, stream>>>(c1, w2c, b2c, xq);
  k_fc1<<<dim3(512), dim3(256), 0, stream>>>(xq, fw1, part);
  k_fc1_reduce<<<dim3(1024), dim3(256), 0, stream>>>(part, fb1, cur3);
  k_lif<<<dim3(256), dim3(512), 0, stream>>>(cur3, w2t, fb2, fw3, fb3, out);
}